// Round 18
// baseline (278.619 us; speedup 1.0000x reference)
//
#include <hip/hip_runtime.h>
#include <hip/hip_bf16.h>
#include <math.h>

#define NEG_ATT 0.2f
#define NEG_ACT 0.01f
#define SHIFT_C 16.0f
#define CHUNK_E 8192
#define STAGE_MAX 12544

typedef __hip_bfloat16  bf16;
typedef unsigned short u16;
typedef short s8v __attribute__((ext_vector_type(8)));
typedef float f4v __attribute__((ext_vector_type(4)));

__device__ __forceinline__ float bflo(unsigned w) { return __uint_as_float(w << 16); }
__device__ __forceinline__ float bfhi(unsigned w) { return __uint_as_float(w & 0xFFFF0000u); }
__device__ __forceinline__ float lrelu_att(float a) { return fmaxf(a, NEG_ATT * a); }
__device__ __forceinline__ u16 f2b(float v) { bf16 h = __float2bfloat16(v); return *(u16*)&h; }

// ============================ MFMA GEMM body (gemm1, used inside k_front) ============================
__device__ __forceinline__ void gemm1_body(int bx, const float* __restrict__ in,
                                           const u16* __restrict__ Wp,
                                           bf16* __restrict__ ob,
                                           float* __restrict__ o1, float* __restrict__ o2, int N) {
    __shared__ u16 As[64][136];
    const int tid = threadIdx.x;
    const int w = tid >> 6, lane = tid & 63;
    const int row0 = bx * 64;
    for (int i = tid; i < 64 * 128; i += 256) {
        int rl = i >> 7, k = i & 127;
        int n = row0 + rl;
        As[rl][k] = f2b((n < N) ? in[(size_t)n * 128 + k] : 0.f);
    }
    __syncthreads();
    const int rloc = w * 16 + (lane & 15);
    const int kgrp = lane >> 4;
    s8v af[4];
    #pragma unroll
    for (int kk = 0; kk < 4; ++kk)
        af[kk] = *(const s8v*)&As[rloc][kk * 32 + kgrp * 8];
    #pragma unroll
    for (int ct = 0; ct < 9; ++ct) {
        f4v acc = {0.f, 0.f, 0.f, 0.f};
        #pragma unroll
        for (int kk = 0; kk < 4; ++kk) {
            s8v b = *(const s8v*)&Wp[(size_t)((ct * 4 + kk) * 64 + lane) * 8];
            acc = __builtin_amdgcn_mfma_f32_16x16x32_bf16(af[kk], b, acc, 0, 0, 0);
        }
        const int colb = ct * 16 + (lane & 15);
        #pragma unroll
        for (int r = 0; r < 4; ++r) {
            int n = row0 + w * 16 + kgrp * 4 + r;
            if (n >= N) continue;
            float val = acc[r];
            if (colb < 128)      ob[(size_t)n * 128 + colb] = __float2bfloat16(val);
            else if (colb < 132) o1[n * 4 + (colb - 128)] = val;
            else if (colb < 136) o2[n * 4 + (colb - 132)] = val;
        }
    }
}

// ============================ fused pack + bhist zero ============================
__global__ void k_packz(const float* __restrict__ W1, const float* __restrict__ a1sw,
                        const float* __restrict__ a1dw,
                        const float* __restrict__ W2, const float* __restrict__ a2sw,
                        const float* __restrict__ a2dw,
                        const float* __restrict__ Wd1,
                        u16* __restrict__ Wp1, u16* __restrict__ Wp2, u16* __restrict__ Wpd,
                        int* __restrict__ bhist) {
    if (blockIdx.x == 48) {
        if (threadIdx.x < 257) bhist[threadIdx.x] = 0;
        return;
    }
    const int T1 = 9 * 4 * 64 * 8, T2 = 5 * 4 * 64 * 8, TD = 4 * 2 * 64 * 8;
    for (int gi = blockIdx.x * 256 + threadIdx.x; gi < T1 + T2 + TD; gi += 48 * 256) {
        if (gi < T1) {
            int i = gi;
            int ct = i >> 11, rem = i & 2047;
            int kk = rem >> 9, l = (rem >> 3) & 63, j = i & 7;
            int k = kk * 32 + ((l >> 4) << 3) + j;
            int c = ct * 16 + (l & 15);
            float v = 0.f;
            if (c < 128) v = W1[k * 128 + c];
            else if (c < 132) {
                int h = c - 128;
                for (int q = 0; q < 32; ++q) v += W1[k * 128 + h * 32 + q] * a1sw[h * 32 + q];
            } else if (c < 136) {
                int h = c - 132;
                for (int q = 0; q < 32; ++q) v += W1[k * 128 + h * 32 + q] * a1dw[h * 32 + q];
            }
            Wp1[i] = f2b(v);
        } else if (gi < T1 + T2) {
            int i = gi - T1;
            int ct = i >> 11, rem = i & 2047;
            int kk = rem >> 9, l = (rem >> 3) & 63, j = i & 7;
            int k = kk * 32 + ((l >> 4) << 3) + j;
            int c = ct * 16 + (l & 15);
            float v = 0.f;
            if (c < 64) v = W2[k * 64 + c];
            else if (c == 64) { for (int q = 0; q < 64; ++q) v += W2[k * 64 + q] * a2sw[q]; }
            else if (c == 65) { for (int q = 0; q < 64; ++q) v += W2[k * 64 + q] * a2dw[q]; }
            Wp2[i] = f2b(v);
        } else {
            int i = gi - T1 - T2;
            int ct = i >> 10, rem = i & 1023;
            int kk = rem >> 9, l = (rem >> 3) & 63, j = i & 7;
            int k = kk * 32 + ((l >> 4) << 3) + j;
            int c = ct * 16 + (l & 15);
            float v = (c < 32) ? Wd1[k * 32 + c] : Wd1[(64 + k) * 32 + (c - 32)];
            Wpd[i] = f2b(v);
        }
    }
}

// ============================ fused front: dst-histogram (512 blocks) || gemm1 MFMA ============================
__global__ void k_front(const int* __restrict__ ei, int E, int N, int* __restrict__ bhist,
                        const float* __restrict__ x, const u16* __restrict__ Wp1,
                        bf16* __restrict__ h1b, float* __restrict__ a1s, float* __restrict__ a1d) {
    if (blockIdx.x < 512) {
        __shared__ int h[256];
        h[threadIdx.x] = 0;
        __syncthreads();
        const long E2 = (long)E + N;
        for (long e = (long)blockIdx.x * 256 + threadIdx.x; e < E2; e += 512L * 256) {
            int d = (e < E) ? ei[E + e] : (int)(e - E);
            atomicAdd(&h[d >> 8], 1);
        }
        __syncthreads();
        if (h[threadIdx.x]) atomicAdd(&bhist[threadIdx.x], h[threadIdx.x]);
    } else {
        gemm1_body(blockIdx.x - 512, x, Wp1, h1b, a1s, a1d, N);
    }
}

// ============================ CSR build ============================
__global__ void k_scanA(const int* __restrict__ bhist, int NBKT, int total,
                        int* __restrict__ bbase, int* __restrict__ bcur,
                        int* __restrict__ rowptr, int N) {
    __shared__ int ps[256];
    const int t = threadIdx.x;
    int v = (t < NBKT) ? bhist[t] : 0;
    ps[t] = v;
    __syncthreads();
    for (int off = 1; off < 256; off <<= 1) {
        int u = (t >= off) ? ps[t - off] : 0;
        __syncthreads();
        ps[t] += u;
        __syncthreads();
    }
    int ex = ps[t] - v;
    if (t < NBKT) { bbase[t] = ex; bcur[t] = ex; }
    if (t == 0) { bbase[NBKT] = total; rowptr[N] = total; }
}

__global__ void k_scatterA(const int* __restrict__ ei, int E, int N,
                           int* __restrict__ bcur, unsigned* __restrict__ pk) {
    __shared__ int cnt[256], offs[256], cur[256], gpos[256], ps[256];
    const int tid = threadIdx.x;
    const long E2 = (long)E + N;
    const long chunk0 = (long)blockIdx.x * CHUNK_E;
    const int cmax = (int)min((long)CHUNK_E, E2 - chunk0);
    cnt[tid] = 0;
    __syncthreads();
    for (int i = tid; i < cmax; i += 256) {
        long e = chunk0 + i;
        int d = (e < E) ? ei[E + e] : (int)(e - E);
        atomicAdd(&cnt[d >> 8], 1);
    }
    __syncthreads();
    int v = cnt[tid];
    ps[tid] = v;
    __syncthreads();
    for (int off = 1; off < 256; off <<= 1) {
        int u = (tid >= off) ? ps[tid - off] : 0;
        __syncthreads();
        ps[tid] += u;
        __syncthreads();
    }
    offs[tid] = ps[tid] - v;
    cur[tid]  = ps[tid] - v;
    gpos[tid] = atomicAdd(&bcur[tid], v);
    __syncthreads();
    for (int i = tid; i < cmax; i += 256) {
        long e = chunk0 + i;
        int d, s;
        if (e < E) { d = ei[E + e]; s = ei[e]; } else { d = s = (int)(e - E); }
        int b = d >> 8;
        int r = atomicAdd(&cur[b], 1);
        pk[gpos[b] + (r - offs[b])] = ((unsigned)(d & 255) << 16) | (unsigned)s;
    }
}

__global__ void k_scatterB(const unsigned* __restrict__ pk, const int* __restrict__ bbase,
                           int N, int* __restrict__ rowptr, u16* __restrict__ col) {
    __shared__ int hist[256], loff[256], lcur[256], ps[256];
    __shared__ u16 stage[STAGE_MAX];
    const int b = blockIdx.x;
    const int tid = threadIdx.x;
    const int ebeg = bbase[b], eend = bbase[b + 1];
    const int cnt = eend - ebeg;
    hist[tid] = 0;
    __syncthreads();
    for (int i = tid; i < cnt; i += 256) {
        unsigned p = pk[ebeg + i];
        atomicAdd(&hist[(p >> 16) & 255], 1);
    }
    __syncthreads();
    int v = hist[tid];
    ps[tid] = v;
    __syncthreads();
    for (int off = 1; off < 256; off <<= 1) {
        int u = (tid >= off) ? ps[tid - off] : 0;
        __syncthreads();
        ps[tid] += u;
        __syncthreads();
    }
    loff[tid] = ps[tid] - v;
    lcur[tid] = ps[tid] - v;
    const int n0 = b << 8;
    if (n0 + tid < N) rowptr[n0 + tid] = ebeg + loff[tid];
    __syncthreads();
    if (cnt <= STAGE_MAX) {
        for (int i = tid; i < cnt; i += 256) {
            unsigned p = pk[ebeg + i];
            int r = atomicAdd(&lcur[(p >> 16) & 255], 1);
            stage[r] = (u16)(p & 0xFFFFu);
        }
        __syncthreads();
        for (int i = tid; i < cnt; i += 256) col[ebeg + i] = stage[i];
    } else {
        for (int i = tid; i < cnt; i += 256) {
            unsigned p = pk[ebeg + i];
            int r = atomicAdd(&lcur[(p >> 16) & 255], 1);
            col[ebeg + r] = (u16)(p & 0xFFFFu);
        }
    }
}

// ============================ fused layer 1: aggregate (16 dst/wave) + gemm2 MFMA ============================
__global__ void k_l1(const int* __restrict__ rowptr, const u16* __restrict__ col,
                     const unsigned* __restrict__ h1q, const float* __restrict__ a1s,
                     const float* __restrict__ a1d, const float* __restrict__ b1,
                     const u16* __restrict__ Wp2,
                     bf16* __restrict__ h2b, float* __restrict__ a2s, float* __restrict__ a2d,
                     int N) {
    __shared__ u16 As[64][136];          // leaky(g1) tile, bf16
    __shared__ float als[4][64][4];
    __shared__ int   scol[4][64];
    const int tid = threadIdx.x;
    const int w = tid >> 6, lane = tid & 63;
    const int n0 = blockIdx.x * 64;
    const int hh = lane >> 4;

    for (int sub = 0; sub < 16; ++sub) {
        const int dl = w * 16 + sub;
        const int d = n0 + dl;
        if (d >= N) { *(unsigned*)&As[dl][2 * lane] = 0; continue; }
        const int lo = rowptr[d], hi = rowptr[d + 1];
        const float4 ad4 = *(const float4*)&a1d[d * 4];
        float acc0 = 0.f, acc1 = 0.f;
        float ws0 = 0.f, ws1 = 0.f, ws2 = 0.f, ws3 = 0.f;
        for (int base = lo; base < hi; base += 64) {
            const int cnt = min(64, hi - base);
            if (lane < cnt) {
                int s = col[base + lane];
                float4 as4 = *(const float4*)&a1s[s * 4];
                float a0 = lrelu_att(as4.x + ad4.x) - SHIFT_C;
                float a1 = lrelu_att(as4.y + ad4.y) - SHIFT_C;
                float a2 = lrelu_att(as4.z + ad4.z) - SHIFT_C;
                float a3 = lrelu_att(as4.w + ad4.w) - SHIFT_C;
                float4 al;
                al.x = __expf(a0); al.y = __expf(a1);
                al.z = __expf(a2); al.w = __expf(a3);
                ws0 += al.x; ws1 += al.y; ws2 += al.z; ws3 += al.w;
                *(float4*)&als[w][lane][0] = al;
                scol[w][lane] = s;
            }
            __builtin_amdgcn_wave_barrier();
            int t = 0;
            for (; t + 8 <= cnt; t += 8) {
                unsigned vv[8];
                float aa[8];
                #pragma unroll
                for (int q = 0; q < 8; ++q) {
                    int s = scol[w][t + q];
                    vv[q] = h1q[(((unsigned)s) << 6) | (unsigned)lane];
                    aa[q] = als[w][t + q][hh];
                }
                #pragma unroll
                for (int q = 0; q < 8; ++q) {
                    acc0 = fmaf(bflo(vv[q]), aa[q], acc0);
                    acc1 = fmaf(bfhi(vv[q]), aa[q], acc1);
                }
            }
            for (; t < cnt; ++t) {
                int s = scol[w][t];
                float al = als[w][t][hh];
                unsigned v = h1q[(((unsigned)s) << 6) | (unsigned)lane];
                acc0 = fmaf(bflo(v), al, acc0);
                acc1 = fmaf(bfhi(v), al, acc1);
            }
            __builtin_amdgcn_wave_barrier();
        }
        #pragma unroll
        for (int off = 32; off >= 1; off >>= 1) {
            ws0 += __shfl_xor(ws0, off);
            ws1 += __shfl_xor(ws1, off);
            ws2 += __shfl_xor(ws2, off);
            ws3 += __shfl_xor(ws3, off);
        }
        float wsel = (hh == 0) ? ws0 : (hh == 1) ? ws1 : (hh == 2) ? ws2 : ws3;
        float inv = 1.f / (wsel + 1e-16f);
        float g0 = acc0 * inv + b1[2 * lane];
        float g1v = acc1 * inv + b1[2 * lane + 1];
        g0  = g0  > 0.f ? g0  : NEG_ACT * g0;     // leaky (gemm2 input) in fp32
        g1v = g1v > 0.f ? g1v : NEG_ACT * g1v;
        *(unsigned*)&As[dl][2 * lane] = ((unsigned)f2b(g1v) << 16) | (unsigned)f2b(g0);
    }
    __syncthreads();
    // gemm2: h2 = As @ Wp2 (K=128, CT=5)
    const int rloc = w * 16 + (lane & 15);
    const int kgrp = lane >> 4;
    s8v af[4];
    #pragma unroll
    for (int kk = 0; kk < 4; ++kk)
        af[kk] = *(const s8v*)&As[rloc][kk * 32 + kgrp * 8];
    #pragma unroll
    for (int ct = 0; ct < 5; ++ct) {
        f4v acc = {0.f, 0.f, 0.f, 0.f};
        #pragma unroll
        for (int kk = 0; kk < 4; ++kk) {
            s8v b = *(const s8v*)&Wp2[(size_t)((ct * 4 + kk) * 64 + lane) * 8];
            acc = __builtin_amdgcn_mfma_f32_16x16x32_bf16(af[kk], b, acc, 0, 0, 0);
        }
        const int colb = ct * 16 + (lane & 15);
        #pragma unroll
        for (int r = 0; r < 4; ++r) {
            int n = n0 + w * 16 + kgrp * 4 + r;
            if (n >= N) continue;
            float val = acc[r];
            if (colb < 64)       h2b[(size_t)n * 64 + colb] = __float2bfloat16(val);
            else if (colb == 64) a2s[n] = val;
            else if (colb == 65) a2d[n] = val;
        }
    }
}

// ============================ fused layer 2: aggregate (16 dst/wave) + uv MFMA ============================
__global__ void k_l2(const int* __restrict__ rowptr, const u16* __restrict__ col,
                     const unsigned short* __restrict__ h2s, const float* __restrict__ a2s,
                     const float* __restrict__ a2d, const float* __restrict__ b2,
                     const u16* __restrict__ Wpd, const float* __restrict__ bd1,
                     float* __restrict__ zout, bf16* __restrict__ ub, bf16* __restrict__ vb,
                     int N) {
    __shared__ u16 As[64][72];           // z tile, bf16
    __shared__ float als[4][64];
    __shared__ int   scol[4][64];
    const int tid = threadIdx.x;
    const int w = tid >> 6, lane = tid & 63;
    const int n0 = blockIdx.x * 64;

    for (int sub = 0; sub < 16; ++sub) {
        const int dl = w * 16 + sub;
        const int d = n0 + dl;
        if (d >= N) { As[dl][lane] = 0; continue; }
        const int lo = rowptr[d], hi = rowptr[d + 1];
        const float ad = a2d[d];
        float acc = 0.f, wsum = 0.f;
        for (int base = lo; base < hi; base += 64) {
            const int cnt = min(64, hi - base);
            if (lane < cnt) {
                int s = col[base + lane];
                float a = lrelu_att(a2s[s] + ad) - SHIFT_C;
                float al = __expf(a);
                wsum += al;
                als[w][lane] = al;
                scol[w][lane] = s;
            }
            __builtin_amdgcn_wave_barrier();
            int t = 0;
            for (; t + 8 <= cnt; t += 8) {
                float vv[8], aa[8];
                #pragma unroll
                for (int q = 0; q < 8; ++q) {
                    int s = scol[w][t + q];
                    vv[q] = __uint_as_float((unsigned)h2s[(((unsigned)s) << 6) | (unsigned)lane] << 16);
                    aa[q] = als[w][t + q];
                }
                #pragma unroll
                for (int q = 0; q < 8; ++q) acc = fmaf(vv[q], aa[q], acc);
            }
            for (; t < cnt; ++t) {
                int s = scol[w][t];
                float v = __uint_as_float((unsigned)h2s[(((unsigned)s) << 6) | (unsigned)lane] << 16);
                acc = fmaf(v, als[w][t], acc);
            }
            __builtin_amdgcn_wave_barrier();
        }
        #pragma unroll
        for (int off = 32; off >= 1; off >>= 1) wsum += __shfl_xor(wsum, off);
        float val = acc / (wsum + 1e-16f) + b2[lane];
        zout[(long)d * 64 + lane] = val;      // required output
        As[dl][lane] = f2b(val);
    }
    __syncthreads();
    // uv: [u|v] = As @ Wpd (K=64, CT=4)
    const int rloc = w * 16 + (lane & 15);
    const int kgrp = lane >> 4;
    s8v af[2];
    #pragma unroll
    for (int kk = 0; kk < 2; ++kk)
        af[kk] = *(const s8v*)&As[rloc][kk * 32 + kgrp * 8];
    #pragma unroll
    for (int ct = 0; ct < 4; ++ct) {
        f4v acc = {0.f, 0.f, 0.f, 0.f};
        #pragma unroll
        for (int kk = 0; kk < 2; ++kk) {
            s8v b = *(const s8v*)&Wpd[(size_t)((ct * 2 + kk) * 64 + lane) * 8];
            acc = __builtin_amdgcn_mfma_f32_16x16x32_bf16(af[kk], b, acc, 0, 0, 0);
        }
        const int colb = ct * 16 + (lane & 15);
        #pragma unroll
        for (int r = 0; r < 4; ++r) {
            int n = n0 + w * 16 + kgrp * 4 + r;
            if (n >= N) continue;
            float val = acc[r];
            if (colb < 32) ub[(size_t)n * 32 + colb] = __float2bfloat16(val + bd1[colb]);
            else           vb[(size_t)n * 32 + (colb - 32)] = __float2bfloat16(val);
        }
    }
}

// ============================ decoder per-edge (2-edge ILP) ============================
__global__ void k_dec2(const int* __restrict__ ei, int E,
                       const bf16* __restrict__ u, const bf16* __restrict__ v,
                       const float* __restrict__ Wd2, const float* __restrict__ bd2,
                       float* __restrict__ pred) {
    const int g = threadIdx.x >> 3;
    const int l = threadIdx.x & 7;
    long e0 = (long)blockIdx.x * 64 + g * 2;
    if (e0 >= E) return;
    long e1 = e0 + 1;
    const bool has1 = (e1 < E);
    int s0 = ei[e0], d0 = ei[E + e0];
    int s1 = has1 ? (int)ei[e1] : s0;
    int d1 = has1 ? (int)ei[E + e1] : d0;
    uint2 ua0 = *(const uint2*)(u + (long)s0 * 32 + l * 4);
    uint2 vb0 = *(const uint2*)(v + (long)d0 * 32 + l * 4);
    uint2 ua1 = *(const uint2*)(u + (long)s1 * 32 + l * 4);
    uint2 vb1 = *(const uint2*)(v + (long)d1 * 32 + l * 4);
    float4 wv = *(const float4*)&Wd2[l * 4];
    float p0, p1;
    {
        float h0 = fmaxf(bflo(ua0.x) + bflo(vb0.x), 0.f);
        float h1 = fmaxf(bfhi(ua0.x) + bfhi(vb0.x), 0.f);
        float h2 = fmaxf(bflo(ua0.y) + bflo(vb0.y), 0.f);
        float h3 = fmaxf(bfhi(ua0.y) + bfhi(vb0.y), 0.f);
        p0 = h0 * wv.x;
        p0 = fmaf(h1, wv.y, p0);
        p0 = fmaf(h2, wv.z, p0);
        p0 = fmaf(h3, wv.w, p0);
    }
    {
        float h0 = fmaxf(bflo(ua1.x) + bflo(vb1.x), 0.f);
        float h1 = fmaxf(bfhi(ua1.x) + bfhi(vb1.x), 0.f);
        float h2 = fmaxf(bflo(ua1.y) + bflo(vb1.y), 0.f);
        float h3 = fmaxf(bfhi(ua1.y) + bfhi(vb1.y), 0.f);
        p1 = h0 * wv.x;
        p1 = fmaf(h1, wv.y, p1);
        p1 = fmaf(h2, wv.z, p1);
        p1 = fmaf(h3, wv.w, p1);
    }
    p0 += __shfl_xor(p0, 1, 8);
    p0 += __shfl_xor(p0, 2, 8);
    p0 += __shfl_xor(p0, 4, 8);
    p1 += __shfl_xor(p1, 1, 8);
    p1 += __shfl_xor(p1, 2, 8);
    p1 += __shfl_xor(p1, 4, 8);
    if (l == 0) {
        pred[e0] = p0 + bd2[0];
        if (has1) pred[e1] = p1 + bd2[0];
    }
}

// ============================ launch ============================
extern "C" void kernel_launch(void* const* d_in, const int* in_sizes, int n_in,
                              void* d_out, int out_size, void* d_ws, size_t ws_size,
                              hipStream_t stream) {
    const float* x    = (const float*)d_in[0];
    const int*   ei   = (const int*)d_in[1];
    const float* W1   = (const float*)d_in[2];
    const float* a1sw = (const float*)d_in[3];
    const float* a1dw = (const float*)d_in[4];
    const float* b1   = (const float*)d_in[5];
    const float* W2   = (const float*)d_in[6];
    const float* a2sw = (const float*)d_in[7];
    const float* a2dw = (const float*)d_in[8];
    const float* b2   = (const float*)d_in[9];
    const float* Wd1  = (const float*)d_in[10];
    const float* bd1  = (const float*)d_in[11];
    const float* Wd2  = (const float*)d_in[12];
    const float* bd2  = (const float*)d_in[13];

    const int N = in_sizes[0] / 128;        // 50000
    const int E = in_sizes[1] / 2;          // 1600000
    const int E2 = E + N;
    const int NBKT = (N + 255) >> 8;        // 196

    float* pred = (float*)d_out;            // [E]
    float* zout = (float*)d_out + E;        // [N,64]

    // workspace layout (float-slot units)
    float* W = (float*)d_ws;
    size_t o = 0;
    bf16* h1b  = (bf16*)(W + o); o += (size_t)N * 64;          // N*128 bf16
    bf16* h2b  = (bf16*)(W + o); o += (size_t)N * 32;          // N*64 bf16
    bf16* ub   = (bf16*)(W + o); o += (size_t)N * 16;          // N*32 bf16
    bf16* vb   = (bf16*)(W + o); o += (size_t)N * 16;          // N*32 bf16
    float* a1s = W + o; o += (size_t)N * 4;
    float* a1d = W + o; o += (size_t)N * 4;
    float* a2s = W + o; o += (size_t)N;
    float* a2d = W + o; o += (size_t)N;
    int* rowptr = (int*)(W + o); o += (size_t)N + 1;
    unsigned* pk = (unsigned*)(W + o); o += (size_t)E2;
    u16* col    = (u16*)(W + o); o += ((size_t)E2 + 1) / 2;
    int* bhist  = (int*)(W + o); o += 257;
    int* bbase  = (int*)(W + o); o += 257;
    int* bcur   = (int*)(W + o); o += 257;
    u16* Wp1   = (u16*)(W + o); o += 9216;
    u16* Wp2   = (u16*)(W + o); o += 5120;
    u16* Wpd   = (u16*)(W + o); o += 2048;
    if (ws_size < o * sizeof(float)) return;

    const int TB = 256;
    const int NBLK = (N + 63) >> 6;         // 782

    // 1: pack weights + zero bhist
    k_packz<<<49, TB, 0, stream>>>(W1, a1sw, a1dw, W2, a2sw, a2dw, Wd1, Wp1, Wp2, Wpd, bhist);
    // 2: dst histogram || gemm1 MFMA
    k_front<<<512 + NBLK, TB, 0, stream>>>(ei, E, N, bhist, x, Wp1, h1b, a1s, a1d);
    // 3-5: CSR build
    k_scanA<<<1, TB, 0, stream>>>(bhist, NBKT, E2, bbase, bcur, rowptr, N);
    k_scatterA<<<(E2 + CHUNK_E - 1) / CHUNK_E, TB, 0, stream>>>(ei, E, N, bcur, pk);
    k_scatterB<<<NBKT, TB, 0, stream>>>(pk, bbase, N, rowptr, col);
    // 6: layer-1 aggregate + gemm2 (fused)
    k_l1<<<NBLK, TB, 0, stream>>>(rowptr, col, (const unsigned*)h1b, a1s, a1d, b1,
                                  Wp2, h2b, a2s, a2d, N);
    // 7: layer-2 aggregate + uv (fused)
    k_l2<<<NBLK, TB, 0, stream>>>(rowptr, col, (const unsigned short*)h2b, a2s, a2d, b2,
                                  Wpd, bd1, zout, ub, vb, N);
    // 8: decoder per-edge
    k_dec2<<<(E + 63) / 64, TB, 0, stream>>>(ei, E, ub, vb, Wd2, bd2, pred);
}

// Round 19
// 239.729 us; speedup vs baseline: 1.1622x; 1.1622x over previous
//
#include <hip/hip_runtime.h>
#include <hip/hip_bf16.h>
#include <math.h>

#define NEG_ATT 0.2f
#define NEG_ACT 0.01f
#define SHIFT_C 16.0f
#define CHUNK_E 8192
#define STAGE_MAX 12544

typedef __hip_bfloat16  bf16;
typedef unsigned short u16;
typedef short s8v __attribute__((ext_vector_type(8)));
typedef float f4v __attribute__((ext_vector_type(4)));

__device__ __forceinline__ float bflo(unsigned w) { return __uint_as_float(w << 16); }
__device__ __forceinline__ float bfhi(unsigned w) { return __uint_as_float(w & 0xFFFF0000u); }
__device__ __forceinline__ float lrelu_att(float a) { return fmaxf(a, NEG_ATT * a); }
__device__ __forceinline__ u16 f2b(float v) { bf16 h = __float2bfloat16(v); return *(u16*)&h; }

// ============================ MFMA GEMM body (shared by fused + standalone) ============================
// MODE 0: gemm1 (fp32 in) -> h1b, a1s, a1d ; MODE 1: gemm2 (bf16 in, leaky) -> h2b, a2s, a2d
// MODE 2: uv (fp32 in) -> ub (+bias), vb
template<int MODE, int K, int CT, int INBF>
__device__ __forceinline__ void mfma_body(int bx, const void* __restrict__ in_,
                                          const u16* __restrict__ Wp,
                                          const float* __restrict__ bias,
                                          bf16* __restrict__ ob, bf16* __restrict__ ob2,
                                          float* __restrict__ o1, float* __restrict__ o2, int N) {
    constexpr int KK = K / 32;
    constexpr int KP = K + 8;
    __shared__ u16 As[64][KP];
    const int tid = threadIdx.x;
    const int w = tid >> 6, lane = tid & 63;
    const int row0 = bx * 64;
    for (int i = tid; i < 64 * K; i += 256) {
        int rl = (K == 128) ? (i >> 7) : (i >> 6);
        int k  = i - rl * K;
        int n = row0 + rl;
        float v = 0.f;
        if (n < N) {
            if (INBF) v = __uint_as_float((unsigned)((const u16*)in_)[(size_t)n * K + k] << 16);
            else      v = ((const float*)in_)[(size_t)n * K + k];
        }
        if (MODE == 1) v = v > 0.f ? v : NEG_ACT * v;
        As[rl][k] = f2b(v);
    }
    __syncthreads();
    const int rloc = w * 16 + (lane & 15);
    const int kgrp = lane >> 4;
    s8v af[KK];
    #pragma unroll
    for (int kk = 0; kk < KK; ++kk)
        af[kk] = *(const s8v*)&As[rloc][kk * 32 + kgrp * 8];
    #pragma unroll
    for (int ct = 0; ct < CT; ++ct) {
        f4v acc = {0.f, 0.f, 0.f, 0.f};
        #pragma unroll
        for (int kk = 0; kk < KK; ++kk) {
            s8v b = *(const s8v*)&Wp[(size_t)((ct * KK + kk) * 64 + lane) * 8];
            acc = __builtin_amdgcn_mfma_f32_16x16x32_bf16(af[kk], b, acc, 0, 0, 0);
        }
        const int colb = ct * 16 + (lane & 15);
        #pragma unroll
        for (int r = 0; r < 4; ++r) {
            int n = row0 + w * 16 + kgrp * 4 + r;
            if (n >= N) continue;
            float val = acc[r];
            if (MODE == 0) {
                if (colb < 128)      ob[(size_t)n * 128 + colb] = __float2bfloat16(val);
                else if (colb < 132) o1[n * 4 + (colb - 128)] = val;
                else if (colb < 136) o2[n * 4 + (colb - 132)] = val;
            } else if (MODE == 1) {
                if (colb < 64)       ob[(size_t)n * 64 + colb] = __float2bfloat16(val);
                else if (colb == 64) o1[n] = val;
                else if (colb == 65) o2[n] = val;
            } else {
                if (colb < 32) ob[(size_t)n * 32 + colb] = __float2bfloat16(val + bias[colb]);
                else           ob2[(size_t)n * 32 + (colb - 32)] = __float2bfloat16(val);
            }
        }
    }
}

template<int MODE, int K, int CT, int INBF>
__global__ void k_mfma(const void* __restrict__ in_, const u16* __restrict__ Wp,
                       const float* __restrict__ bias,
                       bf16* __restrict__ ob, bf16* __restrict__ ob2,
                       float* __restrict__ o1, float* __restrict__ o2, int N) {
    mfma_body<MODE, K, CT, INBF>(blockIdx.x, in_, Wp, bias, ob, ob2, o1, o2, N);
}

// ============================ fused pack + bhist zero ============================
// blocks 0..47: pack all three weight sets; block 48: zero bhist.
__global__ void k_packz(const float* __restrict__ W1, const float* __restrict__ a1sw,
                        const float* __restrict__ a1dw,
                        const float* __restrict__ W2, const float* __restrict__ a2sw,
                        const float* __restrict__ a2dw,
                        const float* __restrict__ Wd1,
                        u16* __restrict__ Wp1, u16* __restrict__ Wp2, u16* __restrict__ Wpd,
                        int* __restrict__ bhist) {
    if (blockIdx.x == 48) {
        if (threadIdx.x < 257) bhist[threadIdx.x] = 0;
        return;
    }
    const int T1 = 9 * 4 * 64 * 8, T2 = 5 * 4 * 64 * 8, TD = 4 * 2 * 64 * 8;
    for (int gi = blockIdx.x * 256 + threadIdx.x; gi < T1 + T2 + TD; gi += 48 * 256) {
        if (gi < T1) {
            int i = gi;
            int ct = i >> 11, rem = i & 2047;
            int kk = rem >> 9, l = (rem >> 3) & 63, j = i & 7;
            int k = kk * 32 + ((l >> 4) << 3) + j;
            int c = ct * 16 + (l & 15);
            float v = 0.f;
            if (c < 128) v = W1[k * 128 + c];
            else if (c < 132) {
                int h = c - 128;
                for (int q = 0; q < 32; ++q) v += W1[k * 128 + h * 32 + q] * a1sw[h * 32 + q];
            } else if (c < 136) {
                int h = c - 132;
                for (int q = 0; q < 32; ++q) v += W1[k * 128 + h * 32 + q] * a1dw[h * 32 + q];
            }
            Wp1[i] = f2b(v);
        } else if (gi < T1 + T2) {
            int i = gi - T1;
            int ct = i >> 11, rem = i & 2047;
            int kk = rem >> 9, l = (rem >> 3) & 63, j = i & 7;
            int k = kk * 32 + ((l >> 4) << 3) + j;
            int c = ct * 16 + (l & 15);
            float v = 0.f;
            if (c < 64) v = W2[k * 64 + c];
            else if (c == 64) { for (int q = 0; q < 64; ++q) v += W2[k * 64 + q] * a2sw[q]; }
            else if (c == 65) { for (int q = 0; q < 64; ++q) v += W2[k * 64 + q] * a2dw[q]; }
            Wp2[i] = f2b(v);
        } else {
            int i = gi - T1 - T2;
            int ct = i >> 10, rem = i & 1023;
            int kk = rem >> 9, l = (rem >> 3) & 63, j = i & 7;
            int k = kk * 32 + ((l >> 4) << 3) + j;
            int c = ct * 16 + (l & 15);
            float v = (c < 32) ? Wd1[k * 32 + c] : Wd1[(64 + k) * 32 + (c - 32)];
            Wpd[i] = f2b(v);
        }
    }
}

// ============================ fused front: dst-histogram (512 blocks) || gemm1 MFMA ============================
__global__ void k_front(const int* __restrict__ ei, int E, int N, int* __restrict__ bhist,
                        const float* __restrict__ x, const u16* __restrict__ Wp1,
                        bf16* __restrict__ h1b, float* __restrict__ a1s, float* __restrict__ a1d) {
    if (blockIdx.x < 512) {
        __shared__ int h[256];
        h[threadIdx.x] = 0;
        __syncthreads();
        const long E2 = (long)E + N;
        for (long e = (long)blockIdx.x * 256 + threadIdx.x; e < E2; e += 512L * 256) {
            int d = (e < E) ? ei[E + e] : (int)(e - E);
            atomicAdd(&h[d >> 8], 1);
        }
        __syncthreads();
        if (h[threadIdx.x]) atomicAdd(&bhist[threadIdx.x], h[threadIdx.x]);
    } else {
        mfma_body<0, 128, 9, 0>(blockIdx.x - 512, x, Wp1, nullptr, h1b, h1b, a1s, a1d, N);
    }
}

// ============================ CSR build (scan + 2-level bucket scatter) ============================
__global__ void k_scanA(const int* __restrict__ bhist, int NBKT, int total,
                        int* __restrict__ bbase, int* __restrict__ bcur,
                        int* __restrict__ rowptr, int N) {
    __shared__ int ps[256];
    const int t = threadIdx.x;
    int v = (t < NBKT) ? bhist[t] : 0;
    ps[t] = v;
    __syncthreads();
    for (int off = 1; off < 256; off <<= 1) {
        int u = (t >= off) ? ps[t - off] : 0;
        __syncthreads();
        ps[t] += u;
        __syncthreads();
    }
    int ex = ps[t] - v;
    if (t < NBKT) { bbase[t] = ex; bcur[t] = ex; }
    if (t == 0) { bbase[NBKT] = total; rowptr[N] = total; }
}

__global__ void k_scatterA(const int* __restrict__ ei, int E, int N,
                           int* __restrict__ bcur, unsigned* __restrict__ pk) {
    __shared__ int cnt[256], offs[256], cur[256], gpos[256], ps[256];
    const int tid = threadIdx.x;
    const long E2 = (long)E + N;
    const long chunk0 = (long)blockIdx.x * CHUNK_E;
    const int cmax = (int)min((long)CHUNK_E, E2 - chunk0);
    cnt[tid] = 0;
    __syncthreads();
    for (int i = tid; i < cmax; i += 256) {
        long e = chunk0 + i;
        int d = (e < E) ? ei[E + e] : (int)(e - E);
        atomicAdd(&cnt[d >> 8], 1);
    }
    __syncthreads();
    int v = cnt[tid];
    ps[tid] = v;
    __syncthreads();
    for (int off = 1; off < 256; off <<= 1) {
        int u = (tid >= off) ? ps[tid - off] : 0;
        __syncthreads();
        ps[tid] += u;
        __syncthreads();
    }
    offs[tid] = ps[tid] - v;
    cur[tid]  = ps[tid] - v;
    gpos[tid] = atomicAdd(&bcur[tid], v);
    __syncthreads();
    for (int i = tid; i < cmax; i += 256) {
        long e = chunk0 + i;
        int d, s;
        if (e < E) { d = ei[E + e]; s = ei[e]; } else { d = s = (int)(e - E); }
        int b = d >> 8;
        int r = atomicAdd(&cur[b], 1);
        pk[gpos[b] + (r - offs[b])] = ((unsigned)(d & 255) << 16) | (unsigned)s;
    }
}

__global__ void k_scatterB(const unsigned* __restrict__ pk, const int* __restrict__ bbase,
                           int N, int* __restrict__ rowptr, u16* __restrict__ col) {
    __shared__ int hist[256], loff[256], lcur[256], ps[256];
    __shared__ u16 stage[STAGE_MAX];
    const int b = blockIdx.x;
    const int tid = threadIdx.x;
    const int ebeg = bbase[b], eend = bbase[b + 1];
    const int cnt = eend - ebeg;
    hist[tid] = 0;
    __syncthreads();
    for (int i = tid; i < cnt; i += 256) {
        unsigned p = pk[ebeg + i];
        atomicAdd(&hist[(p >> 16) & 255], 1);
    }
    __syncthreads();
    int v = hist[tid];
    ps[tid] = v;
    __syncthreads();
    for (int off = 1; off < 256; off <<= 1) {
        int u = (tid >= off) ? ps[tid - off] : 0;
        __syncthreads();
        ps[tid] += u;
        __syncthreads();
    }
    loff[tid] = ps[tid] - v;
    lcur[tid] = ps[tid] - v;
    const int n0 = b << 8;
    if (n0 + tid < N) rowptr[n0 + tid] = ebeg + loff[tid];
    __syncthreads();
    if (cnt <= STAGE_MAX) {
        for (int i = tid; i < cnt; i += 256) {
            unsigned p = pk[ebeg + i];
            int r = atomicAdd(&lcur[(p >> 16) & 255], 1);
            stage[r] = (u16)(p & 0xFFFFu);
        }
        __syncthreads();
        for (int i = tid; i < cnt; i += 256) col[ebeg + i] = stage[i];
    } else {
        for (int i = tid; i < cnt; i += 256) {
            unsigned p = pk[ebeg + i];
            int r = atomicAdd(&lcur[(p >> 16) & 255], 1);
            col[ebeg + r] = (u16)(p & 0xFFFFu);
        }
    }
}

// ============================ layer-1 aggregate (fixed shift, unroll 8, bf16 out) ============================
__global__ void k_aggr1(const int* __restrict__ rowptr, const u16* __restrict__ col,
                        const unsigned* __restrict__ h1q, const float* __restrict__ a1s,
                        const float* __restrict__ a1d, const float* __restrict__ b1,
                        unsigned* __restrict__ g1b, int N) {
    __shared__ float als[4][64][4];
    __shared__ int   scol[4][64];
    const int w = threadIdx.x >> 6;
    const int lane = threadIdx.x & 63;
    const int d = blockIdx.x * 4 + w;
    if (d >= N) return;
    const int lo = rowptr[d], hi = rowptr[d + 1];
    const float4 ad4 = *(const float4*)&a1d[d * 4];

    const int hh = lane >> 4;
    float acc0 = 0.f, acc1 = 0.f;
    float ws0 = 0.f, ws1 = 0.f, ws2 = 0.f, ws3 = 0.f;
    for (int base = lo; base < hi; base += 64) {
        const int cnt = min(64, hi - base);
        if (lane < cnt) {
            int s = col[base + lane];
            float4 as4 = *(const float4*)&a1s[s * 4];
            float a0 = lrelu_att(as4.x + ad4.x) - SHIFT_C;
            float a1 = lrelu_att(as4.y + ad4.y) - SHIFT_C;
            float a2 = lrelu_att(as4.z + ad4.z) - SHIFT_C;
            float a3 = lrelu_att(as4.w + ad4.w) - SHIFT_C;
            float4 al;
            al.x = __expf(a0); al.y = __expf(a1);
            al.z = __expf(a2); al.w = __expf(a3);
            ws0 += al.x; ws1 += al.y; ws2 += al.z; ws3 += al.w;
            *(float4*)&als[w][lane][0] = al;
            scol[w][lane] = s;
        }
        __builtin_amdgcn_wave_barrier();
        int t = 0;
        for (; t + 8 <= cnt; t += 8) {
            unsigned vv[8];
            float aa[8];
            #pragma unroll
            for (int q = 0; q < 8; ++q) {
                int s = scol[w][t + q];
                vv[q] = h1q[(((unsigned)s) << 6) | (unsigned)lane];
                aa[q] = als[w][t + q][hh];
            }
            #pragma unroll
            for (int q = 0; q < 8; ++q) {
                acc0 = fmaf(bflo(vv[q]), aa[q], acc0);
                acc1 = fmaf(bfhi(vv[q]), aa[q], acc1);
            }
        }
        for (; t < cnt; ++t) {
            int s = scol[w][t];
            float al = als[w][t][hh];
            unsigned v = h1q[(((unsigned)s) << 6) | (unsigned)lane];
            acc0 = fmaf(bflo(v), al, acc0);
            acc1 = fmaf(bfhi(v), al, acc1);
        }
        __builtin_amdgcn_wave_barrier();
    }
    #pragma unroll
    for (int off = 32; off >= 1; off >>= 1) {
        ws0 += __shfl_xor(ws0, off);
        ws1 += __shfl_xor(ws1, off);
        ws2 += __shfl_xor(ws2, off);
        ws3 += __shfl_xor(ws3, off);
    }
    float wsel = (hh == 0) ? ws0 : (hh == 1) ? ws1 : (hh == 2) ? ws2 : ws3;
    float inv = 1.f / (wsel + 1e-16f);
    unsigned outw = ((unsigned)f2b(acc1 * inv + b1[2 * lane + 1]) << 16)
                  | (unsigned)f2b(acc0 * inv + b1[2 * lane]);
    g1b[(size_t)d * 64 + lane] = outw;
}

// ============================ layer-2 aggregate (fixed shift, unroll 8) ============================
__global__ void k_aggr2(const int* __restrict__ rowptr, const u16* __restrict__ col,
                        const unsigned short* __restrict__ h2s, const float* __restrict__ a2s,
                        const float* __restrict__ a2d, const float* __restrict__ b2,
                        float* __restrict__ zout, int N) {
    __shared__ float als[4][64];
    __shared__ int   scol[4][64];
    const int w = threadIdx.x >> 6;
    const int lane = threadIdx.x & 63;
    const int d = blockIdx.x * 4 + w;
    if (d >= N) return;
    const int lo = rowptr[d], hi = rowptr[d + 1];
    const float ad = a2d[d];

    float acc = 0.f, wsum = 0.f;
    for (int base = lo; base < hi; base += 64) {
        const int cnt = min(64, hi - base);
        if (lane < cnt) {
            int s = col[base + lane];
            float a = lrelu_att(a2s[s] + ad) - SHIFT_C;
            float al = __expf(a);
            wsum += al;
            als[w][lane] = al;
            scol[w][lane] = s;
        }
        __builtin_amdgcn_wave_barrier();
        int t = 0;
        for (; t + 8 <= cnt; t += 8) {
            float vv[8], aa[8];
            #pragma unroll
            for (int q = 0; q < 8; ++q) {
                int s = scol[w][t + q];
                vv[q] = __uint_as_float((unsigned)h2s[(((unsigned)s) << 6) | (unsigned)lane] << 16);
                aa[q] = als[w][t + q];
            }
            #pragma unroll
            for (int q = 0; q < 8; ++q) acc = fmaf(vv[q], aa[q], acc);
        }
        for (; t < cnt; ++t) {
            int s = scol[w][t];
            float v = __uint_as_float((unsigned)h2s[(((unsigned)s) << 6) | (unsigned)lane] << 16);
            acc = fmaf(v, als[w][t], acc);
        }
        __builtin_amdgcn_wave_barrier();
    }
    #pragma unroll
    for (int off = 32; off >= 1; off >>= 1) wsum += __shfl_xor(wsum, off);
    zout[(long)d * 64 + lane] = acc / (wsum + 1e-16f) + b2[lane];
}

// ============================ decoder per-edge (2-edge ILP) ============================
__global__ void k_dec2(const int* __restrict__ ei, int E,
                       const bf16* __restrict__ u, const bf16* __restrict__ v,
                       const float* __restrict__ Wd2, const float* __restrict__ bd2,
                       float* __restrict__ pred) {
    const int g = threadIdx.x >> 3;
    const int l = threadIdx.x & 7;
    long e0 = (long)blockIdx.x * 64 + g * 2;
    if (e0 >= E) return;
    long e1 = e0 + 1;
    const bool has1 = (e1 < E);
    int s0 = ei[e0], d0 = ei[E + e0];
    int s1 = has1 ? (int)ei[e1] : s0;
    int d1 = has1 ? (int)ei[E + e1] : d0;
    uint2 ua0 = *(const uint2*)(u + (long)s0 * 32 + l * 4);
    uint2 vb0 = *(const uint2*)(v + (long)d0 * 32 + l * 4);
    uint2 ua1 = *(const uint2*)(u + (long)s1 * 32 + l * 4);
    uint2 vb1 = *(const uint2*)(v + (long)d1 * 32 + l * 4);
    float4 wv = *(const float4*)&Wd2[l * 4];
    float p0, p1;
    {
        float h0 = fmaxf(bflo(ua0.x) + bflo(vb0.x), 0.f);
        float h1 = fmaxf(bfhi(ua0.x) + bfhi(vb0.x), 0.f);
        float h2 = fmaxf(bflo(ua0.y) + bflo(vb0.y), 0.f);
        float h3 = fmaxf(bfhi(ua0.y) + bfhi(vb0.y), 0.f);
        p0 = h0 * wv.x;
        p0 = fmaf(h1, wv.y, p0);
        p0 = fmaf(h2, wv.z, p0);
        p0 = fmaf(h3, wv.w, p0);
    }
    {
        float h0 = fmaxf(bflo(ua1.x) + bflo(vb1.x), 0.f);
        float h1 = fmaxf(bfhi(ua1.x) + bfhi(vb1.x), 0.f);
        float h2 = fmaxf(bflo(ua1.y) + bflo(vb1.y), 0.f);
        float h3 = fmaxf(bfhi(ua1.y) + bfhi(vb1.y), 0.f);
        p1 = h0 * wv.x;
        p1 = fmaf(h1, wv.y, p1);
        p1 = fmaf(h2, wv.z, p1);
        p1 = fmaf(h3, wv.w, p1);
    }
    p0 += __shfl_xor(p0, 1, 8);
    p0 += __shfl_xor(p0, 2, 8);
    p0 += __shfl_xor(p0, 4, 8);
    p1 += __shfl_xor(p1, 1, 8);
    p1 += __shfl_xor(p1, 2, 8);
    p1 += __shfl_xor(p1, 4, 8);
    if (l == 0) {
        pred[e0] = p0 + bd2[0];
        if (has1) pred[e1] = p1 + bd2[0];
    }
}

// ============================ launch ============================
extern "C" void kernel_launch(void* const* d_in, const int* in_sizes, int n_in,
                              void* d_out, int out_size, void* d_ws, size_t ws_size,
                              hipStream_t stream) {
    const float* x    = (const float*)d_in[0];
    const int*   ei   = (const int*)d_in[1];
    const float* W1   = (const float*)d_in[2];
    const float* a1sw = (const float*)d_in[3];
    const float* a1dw = (const float*)d_in[4];
    const float* b1   = (const float*)d_in[5];
    const float* W2   = (const float*)d_in[6];
    const float* a2sw = (const float*)d_in[7];
    const float* a2dw = (const float*)d_in[8];
    const float* b2   = (const float*)d_in[9];
    const float* Wd1  = (const float*)d_in[10];
    const float* bd1  = (const float*)d_in[11];
    const float* Wd2  = (const float*)d_in[12];
    const float* bd2  = (const float*)d_in[13];

    const int N = in_sizes[0] / 128;        // 50000
    const int E = in_sizes[1] / 2;          // 1600000
    const int E2 = E + N;
    const int NBKT = (N + 255) >> 8;        // 196

    float* pred = (float*)d_out;            // [E]
    float* zout = (float*)d_out + E;        // [N,64]

    // workspace layout (float-slot units)
    float* W = (float*)d_ws;
    size_t o = 0;
    unsigned* g1b = (unsigned*)(W + o); o += (size_t)N * 64;   // N*128 bf16
    bf16* h1b  = (bf16*)(W + o); o += (size_t)N * 64;          // N*128 bf16
    bf16* h2b  = (bf16*)(W + o); o += (size_t)N * 32;          // N*64 bf16
    bf16* ub   = (bf16*)(W + o); o += (size_t)N * 16;          // N*32 bf16
    bf16* vb   = (bf16*)(W + o); o += (size_t)N * 16;          // N*32 bf16
    float* a1s = W + o; o += (size_t)N * 4;
    float* a1d = W + o; o += (size_t)N * 4;
    float* a2s = W + o; o += (size_t)N;
    float* a2d = W + o; o += (size_t)N;
    int* rowptr = (int*)(W + o); o += (size_t)N + 1;
    unsigned* pk = (unsigned*)(W + o); o += (size_t)E2;
    u16* col    = (u16*)(W + o); o += ((size_t)E2 + 1) / 2;
    int* bhist  = (int*)(W + o); o += 257;
    int* bbase  = (int*)(W + o); o += 257;
    int* bcur   = (int*)(W + o); o += 257;
    u16* Wp1   = (u16*)(W + o); o += 9216;
    u16* Wp2   = (u16*)(W + o); o += 5120;
    u16* Wpd   = (u16*)(W + o); o += 2048;
    if (ws_size < o * sizeof(float)) return;

    const int TB = 256;
    const int NBLK = (N + 63) >> 6;

    // 1: pack weights + zero bhist
    k_packz<<<49, TB, 0, stream>>>(W1, a1sw, a1dw, W2, a2sw, a2dw, Wd1, Wp1, Wp2, Wpd, bhist);
    // 2: dst histogram || gemm1 MFMA (independent; fused to overlap)
    k_front<<<512 + NBLK, TB, 0, stream>>>(ei, E, N, bhist, x, Wp1, h1b, a1s, a1d);
    // 3-5: CSR build
    k_scanA<<<1, TB, 0, stream>>>(bhist, NBKT, E2, bbase, bcur, rowptr, N);
    k_scatterA<<<(E2 + CHUNK_E - 1) / CHUNK_E, TB, 0, stream>>>(ei, E, N, bcur, pk);
    k_scatterB<<<NBKT, TB, 0, stream>>>(pk, bbase, N, rowptr, col);
    // 6: layer-1 aggregate
    k_aggr1<<<(N + 3) / 4, TB, 0, stream>>>(rowptr, col, (const unsigned*)h1b, a1s, a1d, b1, g1b, N);
    // 7: gemm2 (bf16 in)
    k_mfma<1, 128, 5, 1><<<NBLK, TB, 0, stream>>>(g1b, Wp2, bd1, h2b, h2b, a2s, a2d, N);
    // 8: layer-2 aggregate
    k_aggr2<<<(N + 3) / 4, TB, 0, stream>>>(rowptr, col, (const unsigned short*)h2b, a2s, a2d, b2, zout, N);
    // 9: decoder uv
    k_mfma<2, 64, 4, 0><<<NBLK, TB, 0, stream>>>(zout, Wpd, bd1, ub, vb, a1s, a1d, N);
    // 10: decoder per-edge
    k_dec2<<<(E + 63) / 64, TB, 0, stream>>>(ei, E, ub, vb, Wd2, bd2, pred);
}